// Round 5
// baseline (161.020 us; speedup 1.0000x reference)
//
#include <hip/hip_runtime.h>

#define MM 4096
#define NN 4096
#define KK 4096
#define BM 256
#define BN 256
#define BK 64
#define NT (KK / BK)

typedef short          s16x8  __attribute__((ext_vector_type(8)));
typedef float          f32x16 __attribute__((ext_vector_type(16)));
typedef unsigned short us4    __attribute__((ext_vector_type(4)));
typedef unsigned short us8    __attribute__((ext_vector_type(8)));

#define MFMA32(a, b, c) __builtin_amdgcn_mfma_f32_32x32x16_bf16((a), (b), (c), 0, 0, 0)
#define SB0() __builtin_amdgcn_sched_barrier(0)
#define LGKM(n) asm volatile("s_waitcnt lgkmcnt(" #n ")" ::: "memory")
#define VMC(n)  asm volatile("s_waitcnt vmcnt(" #n ")" ::: "memory")

// ---------- helpers ----------

__device__ __forceinline__ unsigned short f2bf(float f) {
  unsigned int u = __float_as_uint(f);
  u += 0x7fffu + ((u >> 16) & 1u);
  return (unsigned short)(u >> 16);
}

__device__ __forceinline__ void gload16(const void* g, void* l) {
  __builtin_amdgcn_global_load_lds(
      (const __attribute__((address_space(1))) void*)g,
      (__attribute__((address_space(3))) void*)l, 16, 0, 0);
}

// ---------- kernel 1: 2:4 mask + binarize + cvt -> bf16 W_h (M x K) ----------

__global__ __launch_bounds__(256) void kquant(const float* __restrict__ w,
                                              unsigned short* __restrict__ wh) {
  int idx = blockIdx.x * 256 + threadIdx.x;
  const float4* p = (const float4*)w;
  float4 g0 = p[(size_t)idx * 2];
  float4 g1 = p[(size_t)idx * 2 + 1];
  float v[8] = {g0.x, g0.y, g0.z, g0.w, g1.x, g1.y, g1.z, g1.w};
  us8 o;
#pragma unroll
  for (int g = 0; g < 2; g++) {
    float av[4];
#pragma unroll
    for (int j = 0; j < 4; j++) av[j] = fabsf(v[g * 4 + j]);
#pragma unroll
    for (int j = 0; j < 4; j++) {
      int rank = 0;
#pragma unroll
      for (int k = 0; k < 4; k++) {
        if (k == j) continue;
        rank += (av[k] > av[j] || (av[k] == av[j] && k < j)) ? 1 : 0;
      }
      o[g * 4 + j] = (rank < 2 && v[g * 4 + j] > 0.0f) ? (unsigned short)0x3F80
                                                       : (unsigned short)0;
    }
  }
  *(us8*)(wh + (size_t)idx * 8) = o;
}

// ---------- kernel 2: x (K x N f32) -> xT (N x K bf16) ----------

__global__ __launch_bounds__(256) void ktranspose(const float* __restrict__ x,
                                                  unsigned short* __restrict__ xt) {
  __shared__ float tile[64][65];
  int bn = blockIdx.x;
  int bk = blockIdx.y;
  int t = threadIdx.x;
  int tc = (t & 15) << 2;
  int tr = t >> 4;
  const float* src = x + (size_t)(bk * 64 + tr) * NN + bn * 64 + tc;
#pragma unroll
  for (int i = 0; i < 4; i++) {
    float4 v = *(const float4*)(src + (size_t)i * 16 * NN);
    int r = tr + i * 16;
    tile[r][tc + 0] = v.x; tile[r][tc + 1] = v.y;
    tile[r][tc + 2] = v.z; tile[r][tc + 3] = v.w;
  }
  __syncthreads();
  unsigned short* dst = xt + (size_t)(bn * 64 + tr) * KK + bk * 64 + tc;
#pragma unroll
  for (int i = 0; i < 4; i++) {
    int n = tr + i * 16;
    us4 o;
    o.x = f2bf(tile[tc + 0][n]);
    o.y = f2bf(tile[tc + 1][n]);
    o.z = f2bf(tile[tc + 2][n]);
    o.w = f2bf(tile[tc + 3][n]);
    *(us4*)(dst + (size_t)i * 16 * KK) = o;
  }
}

// ---------- kernel 3: 256x256 GEMM, 32x32x16 MFMA, issue-all/count-paced ----
// 8 waves (2M x 4N), BK=64, dbuf LDS. All 24 tile ds_reads issued at tile
// entry (in-order DS retire), MFMA quadrants paced by LGKM(12)/(8)/(0) so the
// LDS pipe drains UNDER the MFMA pipe. Staging calendar + vmcnt(4) boundaries
// identical to the verified round-3/4 schedule.

__global__ __launch_bounds__(512, 2) void kgemm(const unsigned short* __restrict__ A,
                                                const unsigned short* __restrict__ B,
                                                float* __restrict__ C) {
  __shared__ __align__(16) unsigned short lds[4 * BM * BK];  // A0|A1|B0|B1, 128 KiB

  const int tid  = threadIdx.x;
  const int bmi  = blockIdx.y;
  const int bni  = blockIdx.x;
  const int lane = tid & 63;
  const int wave = tid >> 6;
  const int wm   = wave >> 2;
  const int wn   = wave & 3;
  const int l31  = lane & 31;

  // staging addresses (linear LDS dest; inverse-swizzled global source)
  const int srow  = tid >> 3;
  const int scol  = (tid & 7) << 3;
  const int scolz = scol ^ ((srow & 7) << 3);
  const unsigned short* ga = A + (size_t)(bmi * BM + srow) * KK + scolz;
  const unsigned short* gb = B + (size_t)(bni * BN + srow) * KK + scolz;

  // fragment read offsets (swizzled): row = lane&31, k = (lane>>5)*8 + ks*16
  const int swz   = (lane & 7) << 3;
  const int khalf = (lane >> 5) << 3;
  int ok[4];
#pragma unroll
  for (int ks = 0; ks < 4; ks++) ok[ks] = (ks * 16 + khalf) ^ swz;
  const int arow = (wm * 128 + l31) * BK;   // + mt*32*BK
  const int brow = (wn * 64 + l31) * BK;    // + nt*32*BK

  f32x16 acc[4][2] = {};

  auto stageA = [&](int buf, int t, int h) {
    const unsigned short* p = ga + (size_t)t * BK;
    unsigned short* l = &lds[buf * 16384 + tid * 8];
#pragma unroll
    for (int j = 0; j < 2; j++)
      gload16(p + (size_t)(2 * h + j) * 64 * KK, l + (2 * h + j) * 4096);
  };
  auto stageB = [&](int buf, int t, int h) {
    const unsigned short* p = gb + (size_t)t * BK;
    unsigned short* l = &lds[32768 + buf * 16384 + tid * 8];
#pragma unroll
    for (int j = 0; j < 2; j++)
      gload16(p + (size_t)(2 * h + j) * 64 * KK, l + (2 * h + j) * 4096);
  };

  // prologue: tile 0 -> buf0 (8 loads), A(tile 1) -> buf1 (4 loads)
  stageB(0, 0, 0); stageB(0, 0, 1);
  stageA(0, 0, 0); stageA(0, 0, 1);
  stageA(1, 1, 0); stageA(1, 1, 1);
  VMC(4);                      // tile 0 landed; A(1) in flight
  __builtin_amdgcn_s_barrier();

  s16x8 af[2][4], af2[2][4], b0[4], b1[4];
  const unsigned short* sa0 = &lds[0];
  const unsigned short* sa1 = &lds[16384];
  const unsigned short* sb0 = &lds[32768];
  const unsigned short* sb1 = &lds[32768 + 16384];

  for (int it = 0; it < NT / 2; ++it) {
    const int t1 = 2 * it + 1;
    const int t2 = (2 * it + 2) & (NT - 1);   // wraps on last iter (dead regions)
    const int t3 = (2 * it + 3) & (NT - 1);

    // ================= K-tile 2*it from buf0 =================
    // P1: issue ALL 24 reads (af, b0, b1, af2 in order); stage; gate af+b0; Q00
#pragma unroll
    for (int mt = 0; mt < 2; mt++)
#pragma unroll
      for (int ks = 0; ks < 4; ks++)
        af[mt][ks] = *(const s16x8*)(sa0 + arow + mt * 2048 + ok[ks]);
#pragma unroll
    for (int ks = 0; ks < 4; ks++)
      b0[ks] = *(const s16x8*)(sb0 + brow + ok[ks]);
    SB0();
#pragma unroll
    for (int ks = 0; ks < 4; ks++)
      b1[ks] = *(const s16x8*)(sb0 + brow + 2048 + ok[ks]);
#pragma unroll
    for (int mt = 0; mt < 2; mt++)
#pragma unroll
      for (int ks = 0; ks < 4; ks++)
        af2[mt][ks] = *(const s16x8*)(sa0 + arow + 4096 + mt * 2048 + ok[ks]);
    stageB(1, t1, 0);
    SB0();
    LGKM(12); SB0();
    __builtin_amdgcn_s_setprio(1);
#pragma unroll
    for (int ks = 0; ks < 4; ks++)
#pragma unroll
      for (int mt = 0; mt < 2; mt++)
        acc[mt][0] = MFMA32(af[mt][ks], b0[ks], acc[mt][0]);
    __builtin_amdgcn_s_setprio(0);
    SB0();

    // P2: gate b1; stage; Q01
    LGKM(8); SB0();
    stageB(1, t1, 1);
    SB0();
    __builtin_amdgcn_s_setprio(1);
#pragma unroll
    for (int ks = 0; ks < 4; ks++)
#pragma unroll
      for (int mt = 0; mt < 2; mt++)
        acc[mt][1] = MFMA32(af[mt][ks], b1[ks], acc[mt][1]);
    __builtin_amdgcn_s_setprio(0);
    SB0(); __builtin_amdgcn_s_barrier();

    // P3: gate af2; stage B(t2)->buf0 (B region dead: all B reads issued P1,
    // retired by P2's LGKM(8)+this LGKM, all-waves via P2-end barrier); Q10
    LGKM(0); SB0();
    stageB(0, t2, 0);
    SB0();
    __builtin_amdgcn_s_setprio(1);
#pragma unroll
    for (int ks = 0; ks < 4; ks++)
#pragma unroll
      for (int mt = 0; mt < 2; mt++)
        acc[2 + mt][0] = MFMA32(af2[mt][ks], b0[ks], acc[2 + mt][0]);
    __builtin_amdgcn_s_setprio(0);
    SB0(); __builtin_amdgcn_s_barrier();

    // P4: stage; Q11; boundary vmcnt(4) -> A(t1),B(t1) landed; B(t2) flying
    stageB(0, t2, 1);
    SB0();
    __builtin_amdgcn_s_setprio(1);
#pragma unroll
    for (int ks = 0; ks < 4; ks++)
#pragma unroll
      for (int mt = 0; mt < 2; mt++)
        acc[2 + mt][1] = MFMA32(af2[mt][ks], b1[ks], acc[2 + mt][1]);
    __builtin_amdgcn_s_setprio(0);
    VMC(4);
    SB0(); __builtin_amdgcn_s_barrier();

    // ================= K-tile 2*it+1 from buf1 =================
    // P5: issue all 24 reads; stage A(t2)->buf0 (A dead via P3 barrier); Q00
#pragma unroll
    for (int mt = 0; mt < 2; mt++)
#pragma unroll
      for (int ks = 0; ks < 4; ks++)
        af[mt][ks] = *(const s16x8*)(sa1 + arow + mt * 2048 + ok[ks]);
#pragma unroll
    for (int ks = 0; ks < 4; ks++)
      b0[ks] = *(const s16x8*)(sb1 + brow + ok[ks]);
    SB0();
#pragma unroll
    for (int ks = 0; ks < 4; ks++)
      b1[ks] = *(const s16x8*)(sb1 + brow + 2048 + ok[ks]);
#pragma unroll
    for (int mt = 0; mt < 2; mt++)
#pragma unroll
      for (int ks = 0; ks < 4; ks++)
        af2[mt][ks] = *(const s16x8*)(sa1 + arow + 4096 + mt * 2048 + ok[ks]);
    stageA(0, t2, 0);
    SB0();
    LGKM(12); SB0();
    __builtin_amdgcn_s_setprio(1);
#pragma unroll
    for (int ks = 0; ks < 4; ks++)
#pragma unroll
      for (int mt = 0; mt < 2; mt++)
        acc[mt][0] = MFMA32(af[mt][ks], b0[ks], acc[mt][0]);
    __builtin_amdgcn_s_setprio(0);
    SB0();

    // P6: gate b1; stage; Q01
    LGKM(8); SB0();
    stageA(0, t2, 1);
    SB0();
    __builtin_amdgcn_s_setprio(1);
#pragma unroll
    for (int ks = 0; ks < 4; ks++)
#pragma unroll
      for (int mt = 0; mt < 2; mt++)
        acc[mt][1] = MFMA32(af[mt][ks], b1[ks], acc[mt][1]);
    __builtin_amdgcn_s_setprio(0);
    SB0(); __builtin_amdgcn_s_barrier();

    // P7: gate af2; Q10 (no stage)
    LGKM(0); SB0();
    __builtin_amdgcn_s_setprio(1);
#pragma unroll
    for (int ks = 0; ks < 4; ks++)
#pragma unroll
      for (int mt = 0; mt < 2; mt++)
        acc[2 + mt][0] = MFMA32(af2[mt][ks], b0[ks], acc[2 + mt][0]);
    __builtin_amdgcn_s_setprio(0);
    SB0(); __builtin_amdgcn_s_barrier();

    // P8: stage A(t3)->buf1 (A reads retired by P7 gate + barrier); Q11; vmcnt
    stageA(1, t3, 0);
    stageA(1, t3, 1);
    SB0();
    __builtin_amdgcn_s_setprio(1);
#pragma unroll
    for (int ks = 0; ks < 4; ks++)
#pragma unroll
      for (int mt = 0; mt < 2; mt++)
        acc[2 + mt][1] = MFMA32(af2[mt][ks], b1[ks], acc[2 + mt][1]);
    __builtin_amdgcn_s_setprio(0);
    VMC(4);                    // B(t2),A(t2) landed; A(t3) flying
    SB0(); __builtin_amdgcn_s_barrier();
  }

  // ---- epilogue: D layout col = lane&31, row = (reg&3)+8*(reg>>2)+4*(lane>>5)
  const int rbase = bmi * BM + wm * 128 + ((lane >> 5) << 2);
  const int cbase = bni * BN + wn * 64 + l31;
#pragma unroll
  for (int mt = 0; mt < 4; mt++)
#pragma unroll
    for (int nt = 0; nt < 2; nt++) {
      const int col = cbase + nt * 32;
#pragma unroll
      for (int r = 0; r < 16; r++) {
        int row = rbase + mt * 32 + (r & 3) + 8 * (r >> 2);
        C[(size_t)row * NN + col] = acc[mt][nt][r];
      }
    }
}

// ---------- fallback: fused fp32 tiled GEMM (workspace too small) ----------

__device__ __forceinline__ float binq_elem(const float g[4], int j) {
  float aj = fabsf(g[j]);
  int rank = 0;
#pragma unroll
  for (int k = 0; k < 4; k++) {
    if (k == j) continue;
    float ak = fabsf(g[k]);
    rank += (ak > aj || (ak == aj && k < j)) ? 1 : 0;
  }
  return (rank < 2 && g[j] > 0.0f) ? 1.0f : 0.0f;
}

__global__ __launch_bounds__(256) void kfallback(const float* __restrict__ x,
                                                 const float* __restrict__ w,
                                                 float* __restrict__ c) {
  __shared__ float sA[16][17];
  __shared__ float sB[16][17];
  int tx = threadIdx.x, ty = threadIdx.y;
  int row = blockIdx.y * 16 + ty;
  int col = blockIdx.x * 16 + tx;
  float acc = 0.0f;
  for (int k0 = 0; k0 < KK; k0 += 16) {
    int k = k0 + tx;
    const float* g = &w[(size_t)row * KK + (k & ~3)];
    float gv[4] = {g[0], g[1], g[2], g[3]};
    sA[ty][tx] = binq_elem(gv, k & 3);
    sB[ty][tx] = x[(size_t)(k0 + ty) * NN + col];
    __syncthreads();
#pragma unroll
    for (int kk = 0; kk < 16; kk++) acc += sA[ty][kk] * sB[kk][tx];
    __syncthreads();
  }
  c[(size_t)row * NN + col] = acc;
}

// ---------- launcher ----------

extern "C" void kernel_launch(void* const* d_in, const int* in_sizes, int n_in,
                              void* d_out, int out_size, void* d_ws, size_t ws_size,
                              hipStream_t stream) {
  const float* x = (const float*)d_in[0];
  const float* w = (const float*)d_in[1];
  float* out = (float*)d_out;

  const size_t need = (size_t)MM * KK * 2 + (size_t)NN * KK * 2;
  if (ws_size < need) {
    dim3 blk(16, 16);
    dim3 grd(NN / 16, MM / 16);
    kfallback<<<grd, blk, 0, stream>>>(x, w, out);
    return;
  }

  unsigned short* wh = (unsigned short*)d_ws;
  unsigned short* xt = wh + (size_t)MM * KK;

  kquant<<<(MM * (size_t)KK / 8) / 256, 256, 0, stream>>>(w, wh);
  ktranspose<<<dim3(NN / 64, KK / 64), 256, 0, stream>>>(x, xt);
  kgemm<<<dim3(NN / BN, MM / BM), 512, 0, stream>>>(wh, xt, out);
}

// Round 6
// 133.684 us; speedup vs baseline: 1.2045x; 1.2045x over previous
//
#include <hip/hip_runtime.h>

#define MM 4096
#define NN 4096
#define KK 4096
#define BM 256
#define BN 256
#define BK 64
#define NT (KK / BK)

typedef short          s16x8 __attribute__((ext_vector_type(8)));
typedef float          f32x4 __attribute__((ext_vector_type(4)));
typedef unsigned short us4   __attribute__((ext_vector_type(4)));
typedef unsigned short us8   __attribute__((ext_vector_type(8)));

#define MFMA16(a, b, c) __builtin_amdgcn_mfma_f32_16x16x32_bf16((a), (b), (c), 0, 0, 0)
#define SB0() __builtin_amdgcn_sched_barrier(0)
#define LGKM(n) asm volatile("s_waitcnt lgkmcnt(" #n ")" ::: "memory")
#define VMC(n)  asm volatile("s_waitcnt vmcnt(" #n ")" ::: "memory")

// ---------- helpers ----------

__device__ __forceinline__ unsigned short f2bf(float f) {
  unsigned int u = __float_as_uint(f);
  u += 0x7fffu + ((u >> 16) & 1u);
  return (unsigned short)(u >> 16);
}

__device__ __forceinline__ void gload16(const void* g, void* l) {
  __builtin_amdgcn_global_load_lds(
      (const __attribute__((address_space(1))) void*)g,
      (__attribute__((address_space(3))) void*)l, 16, 0, 0);
}

// ---------- kernel 1: 2:4 mask + binarize + cvt -> bf16 W_h (M x K) ----------

__global__ __launch_bounds__(256) void kquant(const float* __restrict__ w,
                                              unsigned short* __restrict__ wh) {
  int idx = blockIdx.x * 256 + threadIdx.x;
  const float4* p = (const float4*)w;
  float4 g0 = p[(size_t)idx * 2];
  float4 g1 = p[(size_t)idx * 2 + 1];
  float v[8] = {g0.x, g0.y, g0.z, g0.w, g1.x, g1.y, g1.z, g1.w};
  us8 o;
#pragma unroll
  for (int g = 0; g < 2; g++) {
    float av[4];
#pragma unroll
    for (int j = 0; j < 4; j++) av[j] = fabsf(v[g * 4 + j]);
#pragma unroll
    for (int j = 0; j < 4; j++) {
      int rank = 0;
#pragma unroll
      for (int k = 0; k < 4; k++) {
        if (k == j) continue;
        rank += (av[k] > av[j] || (av[k] == av[j] && k < j)) ? 1 : 0;
      }
      o[g * 4 + j] = (rank < 2 && v[g * 4 + j] > 0.0f) ? (unsigned short)0x3F80
                                                       : (unsigned short)0;
    }
  }
  *(us8*)(wh + (size_t)idx * 8) = o;
}

// ---------- kernel 2: x (K x N f32) -> xT (N x K bf16) ----------

__global__ __launch_bounds__(256) void ktranspose(const float* __restrict__ x,
                                                  unsigned short* __restrict__ xt) {
  __shared__ float tile[64][65];
  int bn = blockIdx.x;
  int bk = blockIdx.y;
  int t = threadIdx.x;
  int tc = (t & 15) << 2;
  int tr = t >> 4;
  const float* src = x + (size_t)(bk * 64 + tr) * NN + bn * 64 + tc;
#pragma unroll
  for (int i = 0; i < 4; i++) {
    float4 v = *(const float4*)(src + (size_t)i * 16 * NN);
    int r = tr + i * 16;
    tile[r][tc + 0] = v.x; tile[r][tc + 1] = v.y;
    tile[r][tc + 2] = v.z; tile[r][tc + 3] = v.w;
  }
  __syncthreads();
  unsigned short* dst = xt + (size_t)(bn * 64 + tr) * KK + bk * 64 + tc;
#pragma unroll
  for (int i = 0; i < 4; i++) {
    int n = tr + i * 16;
    us4 o;
    o.x = f2bf(tile[tc + 0][n]);
    o.y = f2bf(tile[tc + 1][n]);
    o.z = f2bf(tile[tc + 2][n]);
    o.w = f2bf(tile[tc + 3][n]);
    *(us4*)(dst + (size_t)i * 16 * KK) = o;
  }
}

// ---------- kernel 3: 256x256 GEMM, minimal-barrier LGKM-paced schedule ----
// 8 waves (2M x 4N), BK=64, dbuf LDS, 16x16x32 MFMA (round-4 0-conflict read
// pattern). ONE barrier + ONE vmcnt per K-tile: all 24 ds_reads issued at
// entry, 8 gloads stage tile t+1, MFMA quadrants paced by LGKM(12)/(8)/(0)
// so the LDS pipe drains UNDER the MFMA pipe and waves desync freely.
// XCD-aware 4x8 block rectangles cut per-XCD L2 operand footprint 36->24 MB.

__global__ __launch_bounds__(512, 2) void kgemm(const unsigned short* __restrict__ A,
                                                const unsigned short* __restrict__ B,
                                                float* __restrict__ C) {
  __shared__ __align__(16) unsigned short lds[4 * BM * BK];  // A0|A1|B0|B1, 128 KiB

  const int tid  = threadIdx.x;
  // XCD swizzle: xcd = bid&7 (round-robin dispatch), give each XCD a 4x8
  // rectangle of the 16x16 block grid (bijective).
  const int bid  = blockIdx.x;
  const int xcd  = bid & 7;
  const int j    = bid >> 3;
  const int bmi  = (xcd >> 1) * 4 + (j >> 3);
  const int bni  = (xcd & 1) * 8 + (j & 7);
  const int lane = tid & 63;
  const int wave = tid >> 6;
  const int wm   = wave >> 2;
  const int wn   = wave & 3;
  const int llo  = lane & 15;
  const int lhi  = lane >> 4;

  // staging addresses (linear LDS dest; inverse-swizzled global source)
  const int srow  = tid >> 3;
  const int scol  = (tid & 7) << 3;
  const int scolz = scol ^ ((srow & 7) << 3);
  const unsigned short* ga = A + (size_t)(bmi * BM + srow) * KK + scolz;
  const unsigned short* gb = B + (size_t)(bni * BN + srow) * KK + scolz;

  // fragment read offsets (swizzled) — round-4 proven 0-conflict pattern
  const int swz  = (llo & 7) << 3;
  const int ok0  = (lhi * 8) ^ swz;
  const int ok1  = (32 + lhi * 8) ^ swz;
  const int arow = (wm * 128 + llo) * BK;
  const int brow = (wn * 64 + llo) * BK;

  f32x4 acc[8][4] = {};

  auto stageA = [&](int buf, int t, int h) {
    const unsigned short* p = ga + (size_t)t * BK;
    unsigned short* l = &lds[buf * 16384 + tid * 8];
#pragma unroll
    for (int jj = 0; jj < 2; jj++)
      gload16(p + (size_t)(2 * h + jj) * 64 * KK, l + (2 * h + jj) * 4096);
  };
  auto stageB = [&](int buf, int t, int h) {
    const unsigned short* p = gb + (size_t)t * BK;
    unsigned short* l = &lds[32768 + buf * 16384 + tid * 8];
#pragma unroll
    for (int jj = 0; jj < 2; jj++)
      gload16(p + (size_t)(2 * h + jj) * 64 * KK, l + (2 * h + jj) * 4096);
  };

  // prologue: tile 0 -> buf0 (8 loads), drain, barrier
  stageA(0, 0, 0); stageA(0, 0, 1);
  stageB(0, 0, 0); stageB(0, 0, 1);
  VMC(0);
  __builtin_amdgcn_s_barrier();

  s16x8 af[4][2], af2[4][2], b0[2][2], b1[2][2];

  for (int t = 0; t < NT; ++t) {
    const int cur = t & 1;
    const unsigned short* sa = &lds[cur * 16384];
    const unsigned short* sb = &lds[32768 + cur * 16384];
    const int tn = (t + 1) & (NT - 1);   // wraps on last iter (dead loads)

    // ---- issue group 1: af (8) + b0 (4) ----
#pragma unroll
    for (int m = 0; m < 4; m++) {
      af[m][0] = *(const s16x8*)(sa + arow + m * 16 * BK + ok0);
      af[m][1] = *(const s16x8*)(sa + arow + m * 16 * BK + ok1);
    }
#pragma unroll
    for (int n = 0; n < 2; n++) {
      b0[n][0] = *(const s16x8*)(sb + brow + n * 16 * BK + ok0);
      b0[n][1] = *(const s16x8*)(sb + brow + n * 16 * BK + ok1);
    }
    SB0();
    // ---- issue group 2: b1 (4) + af2 (8) ----
#pragma unroll
    for (int n = 0; n < 2; n++) {
      b1[n][0] = *(const s16x8*)(sb + brow + (32 + n * 16) * BK + ok0);
      b1[n][1] = *(const s16x8*)(sb + brow + (32 + n * 16) * BK + ok1);
    }
#pragma unroll
    for (int m = 0; m < 4; m++) {
      af2[m][0] = *(const s16x8*)(sa + arow + (64 + m * 16) * BK + ok0);
      af2[m][1] = *(const s16x8*)(sa + arow + (64 + m * 16) * BK + ok1);
    }
    SB0();
    // ---- stage tile t+1 into the other buffer (its last readers, tile t-1,
    // all retired their reads before this tile's entry barrier) ----
    stageA(cur ^ 1, tn, 0); stageA(cur ^ 1, tn, 1);
    stageB(cur ^ 1, tn, 0); stageB(cur ^ 1, tn, 1);
    SB0();

    // ---- Q00: gate first 12 (af+b0) ----
    LGKM(12); SB0();
    __builtin_amdgcn_s_setprio(1);
#pragma unroll
    for (int m = 0; m < 4; m++)
#pragma unroll
      for (int n = 0; n < 2; n++) {
        acc[m][n] = MFMA16(af[m][0], b0[n][0], acc[m][n]);
        acc[m][n] = MFMA16(af[m][1], b0[n][1], acc[m][n]);
      }
    __builtin_amdgcn_s_setprio(0);
    SB0();

    // ---- Q01: gate b1 ----
    LGKM(8); SB0();
    __builtin_amdgcn_s_setprio(1);
#pragma unroll
    for (int m = 0; m < 4; m++)
#pragma unroll
      for (int n = 0; n < 2; n++) {
        acc[m][2 + n] = MFMA16(af[m][0], b1[n][0], acc[m][2 + n]);
        acc[m][2 + n] = MFMA16(af[m][1], b1[n][1], acc[m][2 + n]);
      }
    __builtin_amdgcn_s_setprio(0);
    SB0();

    // ---- Q10 + Q11: gate af2 ----
    LGKM(0); SB0();
    __builtin_amdgcn_s_setprio(1);
#pragma unroll
    for (int m = 0; m < 4; m++)
#pragma unroll
      for (int n = 0; n < 2; n++) {
        acc[4 + m][n] = MFMA16(af2[m][0], b0[n][0], acc[4 + m][n]);
        acc[4 + m][n] = MFMA16(af2[m][1], b0[n][1], acc[4 + m][n]);
      }
#pragma unroll
    for (int m = 0; m < 4; m++)
#pragma unroll
      for (int n = 0; n < 2; n++) {
        acc[4 + m][2 + n] = MFMA16(af2[m][0], b1[n][0], acc[4 + m][2 + n]);
        acc[4 + m][2 + n] = MFMA16(af2[m][1], b1[n][1], acc[4 + m][2 + n]);
      }
    __builtin_amdgcn_s_setprio(0);
    SB0();

    // ---- tile exit: t+1's stage landed (issued ~full tile ago); collective ----
    VMC(0);
    SB0();
    __builtin_amdgcn_s_barrier();
  }

  // ---- epilogue: D layout col = lane&15, row = (lane>>4)*4 + reg ----
  const int crow0 = bmi * BM + wm * 128 + lhi * 4;
  const int ccol0 = bni * BN + wn * 64 + llo;
#pragma unroll
  for (int m = 0; m < 8; m++)
#pragma unroll
    for (int n = 0; n < 4; n++) {
      float* cp = C + (size_t)(crow0 + m * 16) * NN + ccol0 + n * 16;
#pragma unroll
      for (int v = 0; v < 4; v++) cp[(size_t)v * NN] = acc[m][n][v];
    }
}

// ---------- fallback: fused fp32 tiled GEMM (workspace too small) ----------

__device__ __forceinline__ float binq_elem(const float g[4], int j) {
  float aj = fabsf(g[j]);
  int rank = 0;
#pragma unroll
  for (int k = 0; k < 4; k++) {
    if (k == j) continue;
    float ak = fabsf(g[k]);
    rank += (ak > aj || (ak == aj && k < j)) ? 1 : 0;
  }
  return (rank < 2 && g[j] > 0.0f) ? 1.0f : 0.0f;
}

__global__ __launch_bounds__(256) void kfallback(const float* __restrict__ x,
                                                 const float* __restrict__ w,
                                                 float* __restrict__ c) {
  __shared__ float sA[16][17];
  __shared__ float sB[16][17];
  int tx = threadIdx.x, ty = threadIdx.y;
  int row = blockIdx.y * 16 + ty;
  int col = blockIdx.x * 16 + tx;
  float acc = 0.0f;
  for (int k0 = 0; k0 < KK; k0 += 16) {
    int k = k0 + tx;
    const float* g = &w[(size_t)row * KK + (k & ~3)];
    float gv[4] = {g[0], g[1], g[2], g[3]};
    sA[ty][tx] = binq_elem(gv, k & 3);
    sB[ty][tx] = x[(size_t)(k0 + ty) * NN + col];
    __syncthreads();
#pragma unroll
    for (int kk = 0; kk < 16; kk++) acc += sA[ty][kk] * sB[kk][tx];
    __syncthreads();
  }
  c[(size_t)row * NN + col] = acc;
}

// ---------- launcher ----------

extern "C" void kernel_launch(void* const* d_in, const int* in_sizes, int n_in,
                              void* d_out, int out_size, void* d_ws, size_t ws_size,
                              hipStream_t stream) {
  const float* x = (const float*)d_in[0];
  const float* w = (const float*)d_in[1];
  float* out = (float*)d_out;

  const size_t need = (size_t)MM * KK * 2 + (size_t)NN * KK * 2;
  if (ws_size < need) {
    dim3 blk(16, 16);
    dim3 grd(NN / 16, MM / 16);
    kfallback<<<grd, blk, 0, stream>>>(x, w, out);
    return;
  }

  unsigned short* wh = (unsigned short*)d_ws;
  unsigned short* xt = wh + (size_t)MM * KK;

  kquant<<<(MM * (size_t)KK / 8) / 256, 256, 0, stream>>>(w, wh);
  ktranspose<<<dim3(NN / 64, KK / 64), 256, 0, stream>>>(x, xt);
  kgemm<<<dim3((MM / BM) * (NN / BN)), 512, 0, stream>>>(wh, xt, out);
}

// Round 7
// 130.274 us; speedup vs baseline: 1.2360x; 1.0262x over previous
//
#include <hip/hip_runtime.h>

#define MM 4096
#define NN 4096
#define KK 4096
#define BM 256
#define BN 256
#define BK 64
#define NT (KK / BK)

typedef short          s16x8 __attribute__((ext_vector_type(8)));
typedef float          f32x4 __attribute__((ext_vector_type(4)));
typedef unsigned short us4   __attribute__((ext_vector_type(4)));
typedef unsigned short us8   __attribute__((ext_vector_type(8)));

#define MFMA16(a, b, c) __builtin_amdgcn_mfma_f32_16x16x32_bf16((a), (b), (c), 0, 0, 0)
#define SB0() __builtin_amdgcn_sched_barrier(0)
#define LGKM(n) asm volatile("s_waitcnt lgkmcnt(" #n ")" ::: "memory")
#define VMC(n)  asm volatile("s_waitcnt vmcnt(" #n ")" ::: "memory")

// ---------- helpers ----------

__device__ __forceinline__ unsigned short f2bf(float f) {
  unsigned int u = __float_as_uint(f);
  u += 0x7fffu + ((u >> 16) & 1u);
  return (unsigned short)(u >> 16);
}

__device__ __forceinline__ void gload16(const void* g, void* l) {
  __builtin_amdgcn_global_load_lds(
      (const __attribute__((address_space(1))) void*)g,
      (__attribute__((address_space(3))) void*)l, 16, 0, 0);
}

// ---------- kernel 1: 2:4 mask + binarize + cvt -> bf16 W_h (M x K) ----------

__global__ __launch_bounds__(256) void kquant(const float* __restrict__ w,
                                              unsigned short* __restrict__ wh) {
  int idx = blockIdx.x * 256 + threadIdx.x;
  const float4* p = (const float4*)w;
  float4 g0 = p[(size_t)idx * 2];
  float4 g1 = p[(size_t)idx * 2 + 1];
  float v[8] = {g0.x, g0.y, g0.z, g0.w, g1.x, g1.y, g1.z, g1.w};
  us8 o;
#pragma unroll
  for (int g = 0; g < 2; g++) {
    float av[4];
#pragma unroll
    for (int j = 0; j < 4; j++) av[j] = fabsf(v[g * 4 + j]);
#pragma unroll
    for (int j = 0; j < 4; j++) {
      int rank = 0;
#pragma unroll
      for (int k = 0; k < 4; k++) {
        if (k == j) continue;
        rank += (av[k] > av[j] || (av[k] == av[j] && k < j)) ? 1 : 0;
      }
      o[g * 4 + j] = (rank < 2 && v[g * 4 + j] > 0.0f) ? (unsigned short)0x3F80
                                                       : (unsigned short)0;
    }
  }
  *(us8*)(wh + (size_t)idx * 8) = o;
}

// ---------- kernel 2: x (K x N f32) -> xT (N x K bf16) ----------

__global__ __launch_bounds__(256) void ktranspose(const float* __restrict__ x,
                                                  unsigned short* __restrict__ xt) {
  __shared__ float tile[64][65];
  int bn = blockIdx.x;
  int bk = blockIdx.y;
  int t = threadIdx.x;
  int tc = (t & 15) << 2;
  int tr = t >> 4;
  const float* src = x + (size_t)(bk * 64 + tr) * NN + bn * 64 + tc;
#pragma unroll
  for (int i = 0; i < 4; i++) {
    float4 v = *(const float4*)(src + (size_t)i * 16 * NN);
    int r = tr + i * 16;
    tile[r][tc + 0] = v.x; tile[r][tc + 1] = v.y;
    tile[r][tc + 2] = v.z; tile[r][tc + 3] = v.w;
  }
  __syncthreads();
  unsigned short* dst = xt + (size_t)(bn * 64 + tr) * KK + bk * 64 + tc;
#pragma unroll
  for (int i = 0; i < 4; i++) {
    int n = tr + i * 16;
    us4 o;
    o.x = f2bf(tile[tc + 0][n]);
    o.y = f2bf(tile[tc + 1][n]);
    o.z = f2bf(tile[tc + 2][n]);
    o.w = f2bf(tile[tc + 3][n]);
    *(us4*)(dst + (size_t)i * 16 * KK) = o;
  }
}

// ---------- kernel 3: 256x256 GEMM, cross-tile pipelined register loads ----
// 8 waves (2M x 4N), BK=64, dbuf LDS, 16x16x32 MFMA (proven 0-conflict reads).
// One barrier + one vmcnt per K-tile. Next-tile ds_reads split around the
// current tile's LAST MFMA quadrant: [barrier][af+b0(t+1)][Q11(t)][b1+af2(t+1)]
// so the LDS pipe is fed while the MFMA pipe drains, with ZERO extra VGPR
// (new af/b0 reuse regs dead after Q01/Q10; new b1/af2 issued after Q11).

__global__ __launch_bounds__(512, 2) void kgemm(const unsigned short* __restrict__ A,
                                                const unsigned short* __restrict__ B,
                                                float* __restrict__ C) {
  __shared__ __align__(16) unsigned short lds[4 * BM * BK];  // A0|A1|B0|B1, 128 KiB

  const int tid  = threadIdx.x;
  // XCD swizzle: xcd = bid&7; each XCD owns a 4x8 rectangle of the 16x16 grid.
  const int bid  = blockIdx.x;
  const int xcd  = bid & 7;
  const int j    = bid >> 3;
  const int bmi  = (xcd >> 1) * 4 + (j >> 3);
  const int bni  = (xcd & 1) * 8 + (j & 7);
  const int lane = tid & 63;
  const int wave = tid >> 6;
  const int wm   = wave >> 2;
  const int wn   = wave & 3;
  const int llo  = lane & 15;
  const int lhi  = lane >> 4;

  // staging addresses (linear LDS dest; inverse-swizzled global source)
  const int srow  = tid >> 3;
  const int scol  = (tid & 7) << 3;
  const int scolz = scol ^ ((srow & 7) << 3);
  const unsigned short* ga = A + (size_t)(bmi * BM + srow) * KK + scolz;
  const unsigned short* gb = B + (size_t)(bni * BN + srow) * KK + scolz;

  // fragment read offsets (swizzled) — round-4 proven 0-conflict pattern
  const int swz  = (llo & 7) << 3;
  const int ok0  = (lhi * 8) ^ swz;
  const int ok1  = (32 + lhi * 8) ^ swz;
  const int arow = (wm * 128 + llo) * BK;
  const int brow = (wn * 64 + llo) * BK;

  f32x4 acc[8][4] = {};
  s16x8 af[4][2], af2[4][2], b0[2][2], b1[2][2];

  auto stageA = [&](int buf, int t, int h) {
    const unsigned short* p = ga + (size_t)t * BK;
    unsigned short* l = &lds[buf * 16384 + tid * 8];
#pragma unroll
    for (int jj = 0; jj < 2; jj++)
      gload16(p + (size_t)(2 * h + jj) * 64 * KK, l + (2 * h + jj) * 4096);
  };
  auto stageB = [&](int buf, int t, int h) {
    const unsigned short* p = gb + (size_t)t * BK;
    unsigned short* l = &lds[32768 + buf * 16384 + tid * 8];
#pragma unroll
    for (int jj = 0; jj < 2; jj++)
      gload16(p + (size_t)(2 * h + jj) * 64 * KK, l + (2 * h + jj) * 4096);
  };

  // read-issue groups (12 ds_reads each; in-order DS retirement drives LGKM)
  auto readG1 = [&](const unsigned short* sa, const unsigned short* sb) {
#pragma unroll
    for (int m = 0; m < 4; m++) {
      af[m][0] = *(const s16x8*)(sa + arow + m * 16 * BK + ok0);
      af[m][1] = *(const s16x8*)(sa + arow + m * 16 * BK + ok1);
    }
#pragma unroll
    for (int n = 0; n < 2; n++) {
      b0[n][0] = *(const s16x8*)(sb + brow + n * 16 * BK + ok0);
      b0[n][1] = *(const s16x8*)(sb + brow + n * 16 * BK + ok1);
    }
  };
  auto readG2 = [&](const unsigned short* sa, const unsigned short* sb) {
#pragma unroll
    for (int n = 0; n < 2; n++) {
      b1[n][0] = *(const s16x8*)(sb + brow + (32 + n * 16) * BK + ok0);
      b1[n][1] = *(const s16x8*)(sb + brow + (32 + n * 16) * BK + ok1);
    }
#pragma unroll
    for (int m = 0; m < 4; m++) {
      af2[m][0] = *(const s16x8*)(sa + arow + (64 + m * 16) * BK + ok0);
      af2[m][1] = *(const s16x8*)(sa + arow + (64 + m * 16) * BK + ok1);
    }
  };

  // prologue: tile 0 -> buf0; certify; then issue tile-0 reads (24)
  stageA(0, 0, 0); stageA(0, 0, 1);
  stageB(0, 0, 0); stageB(0, 0, 1);
  VMC(0); SB0();
  __builtin_amdgcn_s_barrier(); SB0();
  readG1(&lds[0], &lds[32768]); SB0();
  readG2(&lds[0], &lds[32768]); SB0();

  for (int t = 0; t < NT; ++t) {
    const int cur = t & 1;
    const unsigned short* sa_n = &lds[(cur ^ 1) * 16384];
    const unsigned short* sb_n = &lds[32768 + (cur ^ 1) * 16384];
    const int tn = (t + 1) & (NT - 1);   // wraps on last iter (dead loads/reads)

    // stage tile t+1 into buf^1 (its last readers, tile t-1, retired their
    // reads via LGKM(0) before the previous tile's barrier)
    stageA(cur ^ 1, tn, 0); stageA(cur ^ 1, tn, 1);
    stageB(cur ^ 1, tn, 0); stageB(cur ^ 1, tn, 1);
    SB0();

    // Q00: gate af+b0 (first 12 of the 24 outstanding reads)
    LGKM(12); SB0();
    __builtin_amdgcn_s_setprio(1);
#pragma unroll
    for (int m = 0; m < 4; m++)
#pragma unroll
      for (int n = 0; n < 2; n++) {
        acc[m][n] = MFMA16(af[m][0], b0[n][0], acc[m][n]);
        acc[m][n] = MFMA16(af[m][1], b0[n][1], acc[m][n]);
      }
    __builtin_amdgcn_s_setprio(0);
    SB0();

    // Q01: gate b1
    LGKM(8); SB0();
    __builtin_amdgcn_s_setprio(1);
#pragma unroll
    for (int m = 0; m < 4; m++)
#pragma unroll
      for (int n = 0; n < 2; n++) {
        acc[m][2 + n] = MFMA16(af[m][0], b1[n][0], acc[m][2 + n]);
        acc[m][2 + n] = MFMA16(af[m][1], b1[n][1], acc[m][2 + n]);
      }
    __builtin_amdgcn_s_setprio(0);
    SB0();

    // Q10: gate af2
    LGKM(0); SB0();
    __builtin_amdgcn_s_setprio(1);
#pragma unroll
    for (int m = 0; m < 4; m++)
#pragma unroll
      for (int n = 0; n < 2; n++) {
        acc[4 + m][n] = MFMA16(af2[m][0], b0[n][0], acc[4 + m][n]);
        acc[4 + m][n] = MFMA16(af2[m][1], b0[n][1], acc[4 + m][n]);
      }
    __builtin_amdgcn_s_setprio(0);
    SB0();

    // certify buf^1 (this tile's 8 stage gloads, issued ~2000 cyc ago)
    VMC(0); SB0();
    __builtin_amdgcn_s_barrier(); SB0();

    // issue next-tile group1 (af,b0 regs dead after Q01/Q10 — no extra VGPR)
    readG1(sa_n, sb_n); SB0();

    // Q11 of tile t (uses af2,b1 only) — covers group1's LDS drain
    __builtin_amdgcn_s_setprio(1);
#pragma unroll
    for (int m = 0; m < 4; m++)
#pragma unroll
      for (int n = 0; n < 2; n++) {
        acc[4 + m][2 + n] = MFMA16(af2[m][0], b1[n][0], acc[4 + m][2 + n]);
        acc[4 + m][2 + n] = MFMA16(af2[m][1], b1[n][1], acc[4 + m][2 + n]);
      }
    __builtin_amdgcn_s_setprio(0);
    SB0();

    // issue next-tile group2 (b1,af2 just freed by Q11)
    readG2(sa_n, sb_n); SB0();
  }

  // ---- epilogue: D layout col = lane&15, row = (lane>>4)*4 + reg ----
  const int crow0 = bmi * BM + wm * 128 + lhi * 4;
  const int ccol0 = bni * BN + wn * 64 + llo;
#pragma unroll
  for (int m = 0; m < 8; m++)
#pragma unroll
    for (int n = 0; n < 4; n++) {
      float* cp = C + (size_t)(crow0 + m * 16) * NN + ccol0 + n * 16;
#pragma unroll
      for (int v = 0; v < 4; v++) cp[(size_t)v * NN] = acc[m][n][v];
    }
}

// ---------- fallback: fused fp32 tiled GEMM (workspace too small) ----------

__device__ __forceinline__ float binq_elem(const float g[4], int j) {
  float aj = fabsf(g[j]);
  int rank = 0;
#pragma unroll
  for (int k = 0; k < 4; k++) {
    if (k == j) continue;
    float ak = fabsf(g[k]);
    rank += (ak > aj || (ak == aj && k < j)) ? 1 : 0;
  }
  return (rank < 2 && g[j] > 0.0f) ? 1.0f : 0.0f;
}

__global__ __launch_bounds__(256) void kfallback(const float* __restrict__ x,
                                                 const float* __restrict__ w,
                                                 float* __restrict__ c) {
  __shared__ float sA[16][17];
  __shared__ float sB[16][17];
  int tx = threadIdx.x, ty = threadIdx.y;
  int row = blockIdx.y * 16 + ty;
  int col = blockIdx.x * 16 + tx;
  float acc = 0.0f;
  for (int k0 = 0; k0 < KK; k0 += 16) {
    int k = k0 + tx;
    const float* g = &w[(size_t)row * KK + (k & ~3)];
    float gv[4] = {g[0], g[1], g[2], g[3]};
    sA[ty][tx] = binq_elem(gv, k & 3);
    sB[ty][tx] = x[(size_t)(k0 + ty) * NN + col];
    __syncthreads();
#pragma unroll
    for (int kk = 0; kk < 16; kk++) acc += sA[ty][kk] * sB[kk][tx];
    __syncthreads();
  }
  c[(size_t)row * NN + col] = acc;
}

// ---------- launcher ----------

extern "C" void kernel_launch(void* const* d_in, const int* in_sizes, int n_in,
                              void* d_out, int out_size, void* d_ws, size_t ws_size,
                              hipStream_t stream) {
  const float* x = (const float*)d_in[0];
  const float* w = (const float*)d_in[1];
  float* out = (float*)d_out;

  const size_t need = (size_t)MM * KK * 2 + (size_t)NN * KK * 2;
  if (ws_size < need) {
    dim3 blk(16, 16);
    dim3 grd(NN / 16, MM / 16);
    kfallback<<<grd, blk, 0, stream>>>(x, w, out);
    return;
  }

  unsigned short* wh = (unsigned short*)d_ws;
  unsigned short* xt = wh + (size_t)MM * KK;

  kquant<<<(MM * (size_t)KK / 8) / 256, 256, 0, stream>>>(w, wh);
  ktranspose<<<dim3(NN / 64, KK / 64), 256, 0, stream>>>(x, xt);
  kgemm<<<dim3((MM / BM) * (NN / BN)), 512, 0, stream>>>(wh, xt, out);
}